// Round 8
// baseline (165.981 us; speedup 1.0000x reference)
//
#include <hip/hip_runtime.h>
#include <hip/hip_bf16.h>
#include <math.h>

#define NQ   10880
#define TOK  5440

typedef short s16x8 __attribute__((ext_vector_type(8)));
typedef float f32x4 __attribute__((ext_vector_type(4)));

__device__ __forceinline__ float bf2f_lo(unsigned int u) {
    return __uint_as_float(u << 16);
}
__device__ __forceinline__ float bf2f_hi(unsigned int u) {
    return __uint_as_float(u & 0xFFFF0000u);
}
__device__ __forceinline__ unsigned short f2bf(float f) {
    unsigned int u = __float_as_uint(f);
    u += 0x7FFFu + ((u >> 16) & 1u);
    return (unsigned short)(u >> 16);
}
// packed f32x2 -> bf16x2 (v_cvt_pk_bf16_f32 on gfx950)
__device__ __forceinline__ unsigned int pack2(float a, float b) {
    __hip_bfloat162 h = __float22bfloat162_rn(make_float2(a, b));
    return *reinterpret_cast<unsigned int*>(&h);
}

// ---------------------------------------------------------------------------
// prepW: transpose+convert weights -> WtAll[896][256] bf16.
// rows 0..255: W_val cols; 256..511: W_off; 512..639: W_attn; 640..895: W_out.
// ---------------------------------------------------------------------------
__global__ __launch_bounds__(256) void prepW_k(
    const float* __restrict__ W_val, const float* __restrict__ W_off,
    const float* __restrict__ W_attn, const float* __restrict__ W_out,
    unsigned short* __restrict__ WtAll)
{
    __shared__ unsigned short T[64][72];
    const int bt = blockIdx.x;
    const int tid = threadIdx.x;
    const int kt = bt & 3;
    const int ct = bt >> 2;
    const int c0 = ct * 64;
    const float* Wp; int ldw, cl0;
    if (c0 < 256)      { Wp = W_val;  ldw = 256; cl0 = c0; }
    else if (c0 < 512) { Wp = W_off;  ldw = 256; cl0 = c0 - 256; }
    else if (c0 < 640) { Wp = W_attn; ldw = 128; cl0 = c0 - 512; }
    else               { Wp = W_out;  ldw = 256; cl0 = c0 - 640; }

    const int kk = tid >> 2;
    const int cq = (tid & 3) << 4;
    const float* src = Wp + (size_t)(kt * 64 + kk) * ldw + cl0 + cq;
    float4 f0 = *(const float4*)(src);
    float4 f1 = *(const float4*)(src + 4);
    float4 f2 = *(const float4*)(src + 8);
    float4 f3 = *(const float4*)(src + 12);
    uint4 w0, w1;
    w0.x = pack2(f0.x, f0.y); w0.y = pack2(f0.z, f0.w);
    w0.z = pack2(f1.x, f1.y); w0.w = pack2(f1.z, f1.w);
    w1.x = pack2(f2.x, f2.y); w1.y = pack2(f2.z, f2.w);
    w1.z = pack2(f3.x, f3.y); w1.w = pack2(f3.z, f3.w);
    *(uint4*)&T[kk][cq]     = w0;
    *(uint4*)&T[kk][cq + 8] = w1;
    __syncthreads();
    const int cc = tid >> 2;
    const int kq = (tid & 3) << 4;
    union { unsigned short u[16]; uint4 q[2]; } ob;
#pragma unroll
    for (int j = 0; j < 16; ++j) ob.u[j] = T[kq + j][cc];
    unsigned short* dst = WtAll + (size_t)(c0 + cc) * 256 + kt * 64 + kq;
    *(uint4*)(dst)     = ob.q[0];
    *(uint4*)(dst + 8) = ob.q[1];
}

// ---------------------------------------------------------------------------
// Fused all-bf16 MFMA GEMM, BM=64, BN=128, BK=64, 256 thr (4 waves),
// each wave 32x64 (2x4 of 16x16x32). In-register f32->bf16 (packed cvt).
// grid (170,5): bn 0,1 -> values(bf16) from gathered fm rows;
//               bn 2,3,4 -> offattn(f32) from query rows.
// ---------------------------------------------------------------------------
__global__ __launch_bounds__(256) void gemm_fused_k(
    const float* __restrict__ query, const float* __restrict__ fm,
    const unsigned short* __restrict__ Wt,
    const float* __restrict__ b_val, const float* __restrict__ b_off,
    const float* __restrict__ b_attn,
    unsigned short* __restrict__ values, float* __restrict__ offattn)
{
    __shared__ unsigned short As[64][72];
    __shared__ unsigned short Bs[128][72];

    const int tid = threadIdx.x;
    const int bm = blockIdx.x, bn = blockIdx.y;

    const float* bias;
    void* Cp; int ldc, col0, cbf, wr0;
    if (bn < 2) {
        wr0 = bn * 128; bias = b_val + bn * 128;
        Cp = values; ldc = 256; col0 = bn * 128; cbf = 1;
    } else {
        wr0 = bn * 128;
        bias = (bn == 4) ? b_attn : b_off + (bn - 2) * 128;
        Cp = offattn; ldc = 384; col0 = (bn - 2) * 128; cbf = 0;
    }

    const int arow = tid >> 2;           // 0..63
    const int ac   = (tid & 3) << 4;     // 16-elem k-chunk
    const int r    = bm * 64 + arow;
    const float* a32;
    if (bn < 2) {
        const int b = (r >= TOK) ? 1 : 0;
        const int t = r - b * TOK;
        int l, hh, ww;
        if (t < 4096)      { l = 0; hh = t >> 6; ww = t & 63; }
        else if (t < 5120) { int i = t - 4096; l = 1; hh = i >> 5; ww = i & 31; }
        else if (t < 5376) { int i = t - 5120; l = 2; hh = i >> 4; ww = i & 15; }
        else               { int i = t - 5376; l = 3; hh = i >> 3; ww = i & 7; }
        a32 = fm + ((size_t)((((b * 64 + hh) * 64 + ww) * 4) + l) << 8) + ac;
    } else {
        a32 = query + (size_t)r * 256 + ac;
    }

    const int brow = tid >> 1;           // 0..127
    const int bc   = (tid & 1) << 5;     // 32-elem k-chunk
    const unsigned short* Bp = Wt + (size_t)(wr0 + brow) * 256 + bc;

    const int w = tid >> 6, lane = tid & 63;
    const int quad = lane >> 4, fl = lane & 15;
    const int quad8 = quad << 3;
    const int mW = (w >> 1) << 5;        // 0 or 32
    const int nW = (w & 1) << 6;         // 0 or 64

    f32x4 acc[2][4] = {};

    for (int k0 = 0; k0 < 256; k0 += 64) {
        uint4 av0, av1;
        {
            const float* s = a32 + k0;
            float4 f0 = *(const float4*)(s);
            float4 f1 = *(const float4*)(s + 4);
            float4 f2 = *(const float4*)(s + 8);
            float4 f3 = *(const float4*)(s + 12);
            av0.x = pack2(f0.x, f0.y); av0.y = pack2(f0.z, f0.w);
            av0.z = pack2(f1.x, f1.y); av0.w = pack2(f1.z, f1.w);
            av1.x = pack2(f2.x, f2.y); av1.y = pack2(f2.z, f2.w);
            av1.z = pack2(f3.x, f3.y); av1.w = pack2(f3.z, f3.w);
        }
        uint4 bv0 = *(const uint4*)(Bp + k0);
        uint4 bv1 = *(const uint4*)(Bp + k0 + 8);
        uint4 bv2 = *(const uint4*)(Bp + k0 + 16);
        uint4 bv3 = *(const uint4*)(Bp + k0 + 24);
        __syncthreads();
        *(uint4*)&As[arow][ac]     = av0;
        *(uint4*)&As[arow][ac + 8] = av1;
        *(uint4*)&Bs[brow][bc]      = bv0;
        *(uint4*)&Bs[brow][bc + 8]  = bv1;
        *(uint4*)&Bs[brow][bc + 16] = bv2;
        *(uint4*)&Bs[brow][bc + 24] = bv3;
        __syncthreads();
#pragma unroll
        for (int ks = 0; ks < 64; ks += 32) {
            s16x8 af[2], bf[4];
#pragma unroll
            for (int i = 0; i < 2; ++i)
                af[i] = *(const s16x8*)&As[mW + i * 16 + fl][ks + quad8];
#pragma unroll
            for (int j = 0; j < 4; ++j)
                bf[j] = *(const s16x8*)&Bs[nW + j * 16 + fl][ks + quad8];
#pragma unroll
            for (int i = 0; i < 2; ++i)
#pragma unroll
                for (int j = 0; j < 4; ++j)
                    acc[i][j] = __builtin_amdgcn_mfma_f32_16x16x32_bf16(
                        af[i], bf[j], acc[i][j], 0, 0, 0);
        }
    }

    float* Cf = (float*)Cp;
    unsigned short* Cb = (unsigned short*)Cp;
#pragma unroll
    for (int j = 0; j < 4; ++j) {
        const int c = nW + j * 16 + fl;
        const float bv = bias[c];
        const int cg = col0 + c;
#pragma unroll
        for (int i = 0; i < 2; ++i) {
            const int row0 = bm * 64 + mW + i * 16 + (quad << 2);
#pragma unroll
            for (int rr = 0; rr < 4; ++rr) {
                const float v = acc[i][j][rr] + bv;
                if (cbf) Cb[(size_t)(row0 + rr) * ldc + cg] = f2bf(v);
                else     Cf[(size_t)(row0 + rr) * ldc + cg] = v;
            }
        }
    }
}

// ---------------------------------------------------------------------------
// Fused sampling + out-projection: 8 queries / 256-thread block.
// Stages 1-3 as before (softmax, weight/idx precompute, bilinear gather),
// but stage-3 accumulators go to LDS sQ (bf16, rows 8..15 zero), then a
// per-block MFMA tail computes out[8 x 256] = sQ @ W_out^T + b_out directly
// (A-frags from LDS, B-frags streamed from WtAll rows 640..895, L2-resident).
// Kills the separate out-GEMM dispatch and the qout global round-trip.
// ---------------------------------------------------------------------------
__global__ __launch_bounds__(256) void sampleout_k(
    const float* __restrict__ offattn,          // NQ x 384
    const unsigned short* __restrict__ values,  // (2*TOK) x 256 bf16 compact
    const float* __restrict__ qpos,             // NQ x 2
    const int*   __restrict__ qlevel,           // NQ
    const unsigned short* __restrict__ WtAll,   // rows 640..895 = W_out cols
    const float* __restrict__ b_out,
    float* __restrict__ out)                    // NQ x 256 f32
{
    __shared__ float  sRow[8][384];
    __shared__ float4 sW[8][128];
    __shared__ int4   sIdx[8][128];
    __shared__ unsigned short sQ[16][264];      // +8 pad: b128 reads 2-way free

    const int tid = threadIdx.x;

    // band swizzle (measured-neutral, kept)
    const int band = blockIdx.x & 7;
    const int g    = blockIdx.x >> 3;
    const int bat  = g / 85;
    const int i0   = (g % 85) << 3;
    int qs;
    if (i0 < 512)      qs = band * 512 + i0;
    else if (i0 < 640) qs = 4096 + band * 128 + (i0 - 512);
    else if (i0 < 672) qs = 5120 + band * 32 + (i0 - 640);
    else               qs = 5376 + band * 8;
    const int qbase = bat * TOK + qs;

    {
        const float4* rb = (const float4*)(offattn + (size_t)qbase * 384);
        float4* sf = (float4*)sRow;
#pragma unroll
        for (int i = 0; i < 3; ++i) sf[tid + i * 256] = rb[tid + i * 256];
    }
    // zero pad rows 8..15 of sQ (264 uint4 spanning rows 8..15 contiguously)
    {
        uint4 z = {0u, 0u, 0u, 0u};
        uint4* zp = (uint4*)&sQ[8][0];
        zp[tid] = z;
        if (tid < 8) zp[256 + tid] = z;
    }
    __syncthreads();

    if (tid < 64) {
        const int qn = tid >> 3, h = tid & 7;
        float m = -1e30f;
#pragma unroll
        for (int j = 0; j < 16; ++j) m = fmaxf(m, sRow[qn][256 + j * 8 + h]);
        float e[16], s = 0.f;
#pragma unroll
        for (int j = 0; j < 16; ++j) { e[j] = __expf(sRow[qn][256 + j * 8 + h] - m); s += e[j]; }
        float inv = 1.0f / s;
#pragma unroll
        for (int j = 0; j < 16; ++j) sRow[qn][256 + j * 8 + h] = e[j] * inv;
    }
    __syncthreads();

    const int LBASE[4] = {0, 4096, 5120, 5376};
#pragma unroll
    for (int ss = 0; ss < 4; ++ss) {
        const int s  = tid + ss * 256;
        const int qn = s >> 7;
        const int c  = s & 127;
        const int pl = c >> 3;
        const int l  = pl & 3;
        const int q  = qbase + qn;
        const int b  = (q >= TOK) ? 1 : 0;
        const float ph = qpos[2 * q], pw = qpos[2 * q + 1];
        const int ql = qlevel[q];
        const float invq = 1.0f / (float)(64 >> ql);
        const int Hl = 64 >> l;
        const float Hlf = (float)Hl;
        const float sc = invq * Hlf;
        float lh = ph * sc + sRow[qn][2 * c];
        float lw = pw * sc + sRow[qn][2 * c + 1];
        const float aw = sRow[qn][256 + c];
        lh = fminf(fmaxf(lh, 0.f), Hlf);
        lw = fminf(fmaxf(lw, 0.f), Hlf);
        const float fh0 = floorf(lh), fw0 = floorf(lw);
        const int h0 = (int)fh0, w0 = (int)fw0;
        const float fh = lh - fh0, fw = lw - fw0;
        float w00 = (1.f - fh) * (1.f - fw);
        float w01 = (1.f - fh) * fw;
        float w10 = fh * (1.f - fw);
        float w11 = fh * fw;
        if (h0     >= Hl) { w00 = 0.f; w01 = 0.f; }
        if (h0 + 1 >= Hl) { w10 = 0.f; w11 = 0.f; }
        if (w0     >= Hl) { w00 = 0.f; w10 = 0.f; }
        if (w0 + 1 >= Hl) { w01 = 0.f; w11 = 0.f; }
        const int h0c = min(h0, Hl - 1), h1c = min(h0 + 1, Hl - 1);
        const int w0c = min(w0, Hl - 1), w1c = min(w0 + 1, Hl - 1);
        const int base = b * TOK + LBASE[l];
        sW[qn][c]   = make_float4(aw * w00, aw * w01, aw * w10, aw * w11);
        sIdx[qn][c] = make_int4((base + h0c * Hl + w0c) << 8,
                                (base + h0c * Hl + w1c) << 8,
                                (base + h1c * Hl + w0c) << 8,
                                (base + h1c * Hl + w1c) << 8);
    }
    __syncthreads();

    // stage 3: gather + accumulate -> sQ (bf16)
    {
        const int qn = tid >> 5;
        const int t  = tid & 31;
        const int h  = t >> 2;
        const int dg = t & 3;
        const unsigned short* vb = values + h * 32 + (dg << 3);
        float a[8] = {};
#pragma unroll
        for (int pl = 0; pl < 16; ++pl) {
            const int c = pl * 8 + h;
            const float4 wt = sW[qn][c];
            const int4  id = sIdx[qn][c];
            const uint4 u00 = *(const uint4*)(vb + id.x);
            const uint4 u01 = *(const uint4*)(vb + id.y);
            const uint4 u10 = *(const uint4*)(vb + id.z);
            const uint4 u11 = *(const uint4*)(vb + id.w);
#define ACC8(U, W)                                         \
            a[0] = fmaf(W, bf2f_lo(U.x), a[0]);            \
            a[1] = fmaf(W, bf2f_hi(U.x), a[1]);            \
            a[2] = fmaf(W, bf2f_lo(U.y), a[2]);            \
            a[3] = fmaf(W, bf2f_hi(U.y), a[3]);            \
            a[4] = fmaf(W, bf2f_lo(U.z), a[4]);            \
            a[5] = fmaf(W, bf2f_hi(U.z), a[5]);            \
            a[6] = fmaf(W, bf2f_lo(U.w), a[6]);            \
            a[7] = fmaf(W, bf2f_hi(U.w), a[7]);
            ACC8(u00, wt.x)
            ACC8(u01, wt.y)
            ACC8(u10, wt.z)
            ACC8(u11, wt.w)
#undef ACC8
        }
        uint4 o;
        o.x = pack2(a[0], a[1]);
        o.y = pack2(a[2], a[3]);
        o.z = pack2(a[4], a[5]);
        o.w = pack2(a[6], a[7]);
        *(uint4*)&sQ[qn][h * 32 + (dg << 3)] = o;
    }
    __syncthreads();

    // out-GEMM tail: out[8 x 256] = sQ @ W_out^T + b_out
    // wave w handles 64 output cols; 8 k-tiles x 4 n-tiles of 16x16x32.
    {
        const int wv = tid >> 6, lane = tid & 63;
        const int quad = lane >> 4, fl = lane & 15;
        const int quad8 = quad << 3;
        const unsigned short* Wo = WtAll + (size_t)(640 + wv * 64) * 256;
        f32x4 oacc[4] = {};
#pragma unroll
        for (int kt = 0; kt < 8; ++kt) {
            s16x8 afr = *(const s16x8*)&sQ[fl][kt * 32 + quad8];
#pragma unroll
            for (int nt = 0; nt < 4; ++nt) {
                s16x8 bfr = *(const s16x8*)(Wo + (size_t)(nt * 16 + fl) * 256
                                            + kt * 32 + quad8);
                oacc[nt] = __builtin_amdgcn_mfma_f32_16x16x32_bf16(
                    afr, bfr, oacc[nt], 0, 0, 0);
            }
        }
        if (quad < 2) {
#pragma unroll
            for (int nt = 0; nt < 4; ++nt) {
                const int cg = wv * 64 + nt * 16 + fl;
                const float bv = b_out[cg];
#pragma unroll
                for (int rr = 0; rr < 4; ++rr) {
                    const int q = qbase + (quad << 2) + rr;
                    out[(size_t)q * 256 + cg] = oacc[nt][rr] + bv;
                }
            }
        }
    }
}

// ---------------------------------------------------------------------------
extern "C" void kernel_launch(void* const* d_in, const int* in_sizes, int n_in,
                              void* d_out, int out_size, void* d_ws, size_t ws_size,
                              hipStream_t stream)
{
    const float* query  = (const float*)d_in[0];
    const float* qpos   = (const float*)d_in[1];
    const float* fm     = (const float*)d_in[3];
    const int*   qlvl   = (const int*)d_in[5];
    const float* W_off  = (const float*)d_in[6];
    const float* b_off  = (const float*)d_in[7];
    const float* W_attn = (const float*)d_in[8];
    const float* b_attn = (const float*)d_in[9];
    const float* W_val  = (const float*)d_in[10];
    const float* b_val  = (const float*)d_in[11];
    const float* W_out  = (const float*)d_in[12];
    const float* b_out  = (const float*)d_in[13];
    float* out = (float*)d_out;

    char* ws = (char*)d_ws;
    unsigned short* WtAll   = (unsigned short*)ws;                     // 896*256 bf16
    unsigned short* values  = WtAll + (size_t)896 * 256;               // NQ*256 bf16
    float*          offattn = (float*)(values + (size_t)NQ * 256);     // NQ*384 f32

    dim3 blk(256);
    prepW_k<<<dim3(56), blk, 0, stream>>>(W_val, W_off, W_attn, W_out, WtAll);
    gemm_fused_k<<<dim3(170, 5), blk, 0, stream>>>(query, fm, WtAll,
                                                   b_val, b_off, b_attn,
                                                   values, offattn);
    sampleout_k<<<dim3(NQ / 8), blk, 0, stream>>>(offattn, values, qpos, qlvl,
                                                  WtAll, b_out, out);
}

// Round 9
// 154.772 us; speedup vs baseline: 1.0724x; 1.0724x over previous
//
#include <hip/hip_runtime.h>
#include <hip/hip_bf16.h>
#include <math.h>

#define NQ   10880
#define TOK  5440

typedef short s16x8 __attribute__((ext_vector_type(8)));
typedef float f32x4 __attribute__((ext_vector_type(4)));

__device__ __forceinline__ float bf2f_lo(unsigned int u) {
    return __uint_as_float(u << 16);
}
__device__ __forceinline__ float bf2f_hi(unsigned int u) {
    return __uint_as_float(u & 0xFFFF0000u);
}
__device__ __forceinline__ unsigned short f2bf(float f) {
    unsigned int u = __float_as_uint(f);
    u += 0x7FFFu + ((u >> 16) & 1u);
    return (unsigned short)(u >> 16);
}
// packed f32x2 -> bf16x2 (v_cvt_pk_bf16_f32 on gfx950)
__device__ __forceinline__ unsigned int pack2(float a, float b) {
    __hip_bfloat162 h = __float22bfloat162_rn(make_float2(a, b));
    return *reinterpret_cast<unsigned int*>(&h);
}

// ---------------------------------------------------------------------------
// prepW: transpose+convert weights -> WtAll[896][256] bf16.
// rows 0..255: W_val cols; 256..511: W_off; 512..639: W_attn; 640..895: W_out.
// ---------------------------------------------------------------------------
__global__ __launch_bounds__(256) void prepW_k(
    const float* __restrict__ W_val, const float* __restrict__ W_off,
    const float* __restrict__ W_attn, const float* __restrict__ W_out,
    unsigned short* __restrict__ WtAll)
{
    __shared__ unsigned short T[64][72];
    const int bt = blockIdx.x;
    const int tid = threadIdx.x;
    const int kt = bt & 3;
    const int ct = bt >> 2;
    const int c0 = ct * 64;
    const float* Wp; int ldw, cl0;
    if (c0 < 256)      { Wp = W_val;  ldw = 256; cl0 = c0; }
    else if (c0 < 512) { Wp = W_off;  ldw = 256; cl0 = c0 - 256; }
    else if (c0 < 640) { Wp = W_attn; ldw = 128; cl0 = c0 - 512; }
    else               { Wp = W_out;  ldw = 256; cl0 = c0 - 640; }

    const int kk = tid >> 2;
    const int cq = (tid & 3) << 4;
    const float* src = Wp + (size_t)(kt * 64 + kk) * ldw + cl0 + cq;
    float4 f0 = *(const float4*)(src);
    float4 f1 = *(const float4*)(src + 4);
    float4 f2 = *(const float4*)(src + 8);
    float4 f3 = *(const float4*)(src + 12);
    uint4 w0, w1;
    w0.x = pack2(f0.x, f0.y); w0.y = pack2(f0.z, f0.w);
    w0.z = pack2(f1.x, f1.y); w0.w = pack2(f1.z, f1.w);
    w1.x = pack2(f2.x, f2.y); w1.y = pack2(f2.z, f2.w);
    w1.z = pack2(f3.x, f3.y); w1.w = pack2(f3.z, f3.w);
    *(uint4*)&T[kk][cq]     = w0;
    *(uint4*)&T[kk][cq + 8] = w1;
    __syncthreads();
    const int cc = tid >> 2;
    const int kq = (tid & 3) << 4;
    union { unsigned short u[16]; uint4 q[2]; } ob;
#pragma unroll
    for (int j = 0; j < 16; ++j) ob.u[j] = T[kq + j][cc];
    unsigned short* dst = WtAll + (size_t)(c0 + cc) * 256 + kt * 64 + kq;
    *(uint4*)(dst)     = ob.q[0];
    *(uint4*)(dst + 8) = ob.q[1];
}

// ---------------------------------------------------------------------------
// Fused all-bf16 MFMA GEMM, BM=64, BN=128, BK=64, 256 thr (4 waves),
// each wave 32x64 (2x4 of 16x16x32). In-register f32->bf16 (packed cvt).
// mode 0, grid (170,5): bn 0,1 -> values(bf16) from gathered fm rows;
//                       bn 2,3,4 -> offattn(f32) from query rows.
// mode 1, grid (170,2): out(f32) from qout (bf16 direct).
// ---------------------------------------------------------------------------
__global__ __launch_bounds__(256) void gemm_fused_k(
    const float* __restrict__ query, const float* __restrict__ fm,
    const unsigned short* __restrict__ qoutbf,
    const unsigned short* __restrict__ Wt,
    const float* __restrict__ b_val, const float* __restrict__ b_off,
    const float* __restrict__ b_attn, const float* __restrict__ b_out,
    unsigned short* __restrict__ values, float* __restrict__ offattn,
    float* __restrict__ out, int mode)
{
    __shared__ unsigned short As[64][72];
    __shared__ unsigned short Bs[128][72];

    const int tid = threadIdx.x;
    const int bm = blockIdx.x, bn = blockIdx.y;

    const float* bias;
    void* Cp; int ldc, col0, cbf, wr0;
    if (mode == 0) {
        if (bn < 2) {
            wr0 = bn * 128; bias = b_val + bn * 128;
            Cp = values; ldc = 256; col0 = bn * 128; cbf = 1;
        } else {
            wr0 = bn * 128;
            bias = (bn == 4) ? b_attn : b_off + (bn - 2) * 128;
            Cp = offattn; ldc = 384; col0 = (bn - 2) * 128; cbf = 0;
        }
    } else {
        wr0 = 640 + bn * 128; bias = b_out + bn * 128;
        Cp = out; ldc = 256; col0 = bn * 128; cbf = 0;
    }

    const int asrc = (mode == 1) ? 2 : ((bn < 2) ? 0 : 1);
    const int arow = tid >> 2;           // 0..63
    const int ac   = (tid & 3) << 4;     // 16-elem k-chunk
    const int r    = bm * 64 + arow;
    const float* a32 = nullptr;
    const unsigned short* a16 = nullptr;
    if (asrc == 0) {
        const int b = (r >= TOK) ? 1 : 0;
        const int t = r - b * TOK;
        int l, hh, ww;
        if (t < 4096)      { l = 0; hh = t >> 6; ww = t & 63; }
        else if (t < 5120) { int i = t - 4096; l = 1; hh = i >> 5; ww = i & 31; }
        else if (t < 5376) { int i = t - 5120; l = 2; hh = i >> 4; ww = i & 15; }
        else               { int i = t - 5376; l = 3; hh = i >> 3; ww = i & 7; }
        a32 = fm + ((size_t)((((b * 64 + hh) * 64 + ww) * 4) + l) << 8) + ac;
    } else if (asrc == 1) {
        a32 = query + (size_t)r * 256 + ac;
    } else {
        a16 = qoutbf + (size_t)r * 256 + ac;
    }

    const int brow = tid >> 1;           // 0..127
    const int bc   = (tid & 1) << 5;     // 32-elem k-chunk
    const unsigned short* Bp = Wt + (size_t)(wr0 + brow) * 256 + bc;

    const int w = tid >> 6, lane = tid & 63;
    const int quad = lane >> 4, fl = lane & 15;
    const int quad8 = quad << 3;
    const int mW = (w >> 1) << 5;        // 0 or 32
    const int nW = (w & 1) << 6;         // 0 or 64

    f32x4 acc[2][4] = {};

    for (int k0 = 0; k0 < 256; k0 += 64) {
        uint4 av0, av1;
        if (a16) {
            av0 = *(const uint4*)(a16 + k0);
            av1 = *(const uint4*)(a16 + k0 + 8);
        } else {
            const float* s = a32 + k0;
            float4 f0 = *(const float4*)(s);
            float4 f1 = *(const float4*)(s + 4);
            float4 f2 = *(const float4*)(s + 8);
            float4 f3 = *(const float4*)(s + 12);
            av0.x = pack2(f0.x, f0.y); av0.y = pack2(f0.z, f0.w);
            av0.z = pack2(f1.x, f1.y); av0.w = pack2(f1.z, f1.w);
            av1.x = pack2(f2.x, f2.y); av1.y = pack2(f2.z, f2.w);
            av1.z = pack2(f3.x, f3.y); av1.w = pack2(f3.z, f3.w);
        }
        uint4 bv0 = *(const uint4*)(Bp + k0);
        uint4 bv1 = *(const uint4*)(Bp + k0 + 8);
        uint4 bv2 = *(const uint4*)(Bp + k0 + 16);
        uint4 bv3 = *(const uint4*)(Bp + k0 + 24);
        __syncthreads();
        *(uint4*)&As[arow][ac]     = av0;
        *(uint4*)&As[arow][ac + 8] = av1;
        *(uint4*)&Bs[brow][bc]      = bv0;
        *(uint4*)&Bs[brow][bc + 8]  = bv1;
        *(uint4*)&Bs[brow][bc + 16] = bv2;
        *(uint4*)&Bs[brow][bc + 24] = bv3;
        __syncthreads();
#pragma unroll
        for (int ks = 0; ks < 64; ks += 32) {
            s16x8 af[2], bf[4];
#pragma unroll
            for (int i = 0; i < 2; ++i)
                af[i] = *(const s16x8*)&As[mW + i * 16 + fl][ks + quad8];
#pragma unroll
            for (int j = 0; j < 4; ++j)
                bf[j] = *(const s16x8*)&Bs[nW + j * 16 + fl][ks + quad8];
#pragma unroll
            for (int i = 0; i < 2; ++i)
#pragma unroll
                for (int j = 0; j < 4; ++j)
                    acc[i][j] = __builtin_amdgcn_mfma_f32_16x16x32_bf16(
                        af[i], bf[j], acc[i][j], 0, 0, 0);
        }
    }

    float* Cf = (float*)Cp;
    unsigned short* Cb = (unsigned short*)Cp;
#pragma unroll
    for (int j = 0; j < 4; ++j) {
        const int c = nW + j * 16 + fl;
        const float bv = bias[c];
        const int cg = col0 + c;
#pragma unroll
        for (int i = 0; i < 2; ++i) {
            const int row0 = bm * 64 + mW + i * 16 + (quad << 2);
#pragma unroll
            for (int rr = 0; rr < 4; ++rr) {
                const float v = acc[i][j][rr] + bv;
                if (cbf) Cb[(size_t)(row0 + rr) * ldc + cg] = f2bf(v);
                else     Cf[(size_t)(row0 + rr) * ldc + cg] = v;
            }
        }
    }
}

// ---------------------------------------------------------------------------
// Sampling: 8 queries / 256-thread block, 32 thr/query, XCD-band swizzle.
// LDS cut to 36.9 KB (4 blocks/CU): softmax + stage-2 read offattn directly
// from global (L2-hot) instead of staging 12 KB sRow. Gather loop unrolled
// x2 -> 8 uint4 loads in flight per thread (2x memory-level parallelism).
// ---------------------------------------------------------------------------
__global__ __launch_bounds__(256) void sample_k(
    const float* __restrict__ offattn,          // NQ x 384 (256 off | 128 attn)
    const unsigned short* __restrict__ values,  // (2*TOK) x 256 bf16 compact
    const float* __restrict__ qpos,             // NQ x 2
    const int*   __restrict__ qlevel,           // NQ
    unsigned short* __restrict__ qout)          // NQ x 256 bf16
{
    __shared__ float  sAtt[8][128];
    __shared__ float4 sW[8][128];
    __shared__ int4   sIdx[8][128];

    const int tid = threadIdx.x;

    const int band = blockIdx.x & 7;
    const int g    = blockIdx.x >> 3;
    const int bat  = g / 85;
    const int i0   = (g % 85) << 3;
    int qs;
    if (i0 < 512)      qs = band * 512 + i0;
    else if (i0 < 640) qs = 4096 + band * 128 + (i0 - 512);
    else if (i0 < 672) qs = 5120 + band * 32 + (i0 - 640);
    else               qs = 5376 + band * 8;
    const int qbase = bat * TOK + qs;

    // softmax per (q,h): 64 threads, logits straight from global
    if (tid < 64) {
        const int qn = tid >> 3, h = tid & 7;
        const float* ap = offattn + (size_t)(qbase + qn) * 384 + 256 + h;
        float v[16];
#pragma unroll
        for (int j = 0; j < 16; ++j) v[j] = ap[j * 8];
        float m = -1e30f;
#pragma unroll
        for (int j = 0; j < 16; ++j) m = fmaxf(m, v[j]);
        float e[16], s = 0.f;
#pragma unroll
        for (int j = 0; j < 16; ++j) { e[j] = __expf(v[j] - m); s += e[j]; }
        float inv = 1.0f / s;
#pragma unroll
        for (int j = 0; j < 16; ++j) sAtt[qn][j * 8 + h] = e[j] * inv;
    }
    __syncthreads();

    // stage 2: 1024 (q,p,l,h) sets, 4 per thread; offsets straight from global
    const int LBASE[4] = {0, 4096, 5120, 5376};
#pragma unroll
    for (int ss = 0; ss < 4; ++ss) {
        const int s  = tid + ss * 256;
        const int qn = s >> 7;
        const int c  = s & 127;
        const int pl = c >> 3;
        const int l  = pl & 3;
        const int q  = qbase + qn;
        const int b  = (q >= TOK) ? 1 : 0;
        const float ph = qpos[2 * q], pw = qpos[2 * q + 1];
        const int ql = qlevel[q];
        const float invq = 1.0f / (float)(64 >> ql);
        const int Hl = 64 >> l;
        const float Hlf = (float)Hl;
        const float sc = invq * Hlf;
        const float* offp = offattn + (size_t)q * 384 + 2 * c;
        float lh = ph * sc + offp[0];
        float lw = pw * sc + offp[1];
        const float aw = sAtt[qn][c];
        lh = fminf(fmaxf(lh, 0.f), Hlf);
        lw = fminf(fmaxf(lw, 0.f), Hlf);
        const float fh0 = floorf(lh), fw0 = floorf(lw);
        const int h0 = (int)fh0, w0 = (int)fw0;
        const float fh = lh - fh0, fw = lw - fw0;
        float w00 = (1.f - fh) * (1.f - fw);
        float w01 = (1.f - fh) * fw;
        float w10 = fh * (1.f - fw);
        float w11 = fh * fw;
        if (h0     >= Hl) { w00 = 0.f; w01 = 0.f; }
        if (h0 + 1 >= Hl) { w10 = 0.f; w11 = 0.f; }
        if (w0     >= Hl) { w00 = 0.f; w10 = 0.f; }
        if (w0 + 1 >= Hl) { w01 = 0.f; w11 = 0.f; }
        const int h0c = min(h0, Hl - 1), h1c = min(h0 + 1, Hl - 1);
        const int w0c = min(w0, Hl - 1), w1c = min(w0 + 1, Hl - 1);
        const int base = b * TOK + LBASE[l];
        sW[qn][c]   = make_float4(aw * w00, aw * w01, aw * w10, aw * w11);
        sIdx[qn][c] = make_int4((base + h0c * Hl + w0c) << 8,
                                (base + h0c * Hl + w1c) << 8,
                                (base + h1c * Hl + w0c) << 8,
                                (base + h1c * Hl + w1c) << 8);
    }
    __syncthreads();

    // stage 3: gather + accumulate, pl unrolled x2 (8 loads in flight)
    const int qn = tid >> 5;
    const int t  = tid & 31;
    const int h  = t >> 2;
    const int dg = t & 3;
    const unsigned short* vb = values + h * 32 + (dg << 3);
    float a[8] = {};
#pragma unroll
    for (int pl = 0; pl < 16; pl += 2) {
        const int c0 = pl * 8 + h;
        const int c1 = c0 + 8;
        const float4 wt0 = sW[qn][c0];
        const int4  id0 = sIdx[qn][c0];
        const float4 wt1 = sW[qn][c1];
        const int4  id1 = sIdx[qn][c1];
        const uint4 u00a = *(const uint4*)(vb + id0.x);
        const uint4 u01a = *(const uint4*)(vb + id0.y);
        const uint4 u10a = *(const uint4*)(vb + id0.z);
        const uint4 u11a = *(const uint4*)(vb + id0.w);
        const uint4 u00b = *(const uint4*)(vb + id1.x);
        const uint4 u01b = *(const uint4*)(vb + id1.y);
        const uint4 u10b = *(const uint4*)(vb + id1.z);
        const uint4 u11b = *(const uint4*)(vb + id1.w);
#define ACC8(U, W)                                         \
        a[0] = fmaf(W, bf2f_lo(U.x), a[0]);                \
        a[1] = fmaf(W, bf2f_hi(U.x), a[1]);                \
        a[2] = fmaf(W, bf2f_lo(U.y), a[2]);                \
        a[3] = fmaf(W, bf2f_hi(U.y), a[3]);                \
        a[4] = fmaf(W, bf2f_lo(U.z), a[4]);                \
        a[5] = fmaf(W, bf2f_hi(U.z), a[5]);                \
        a[6] = fmaf(W, bf2f_lo(U.w), a[6]);                \
        a[7] = fmaf(W, bf2f_hi(U.w), a[7]);
        ACC8(u00a, wt0.x)
        ACC8(u01a, wt0.y)
        ACC8(u10a, wt0.z)
        ACC8(u11a, wt0.w)
        ACC8(u00b, wt1.x)
        ACC8(u01b, wt1.y)
        ACC8(u10b, wt1.z)
        ACC8(u11b, wt1.w)
#undef ACC8
    }
    const int q = qbase + qn;
    uint4 o;
    o.x = pack2(a[0], a[1]);
    o.y = pack2(a[2], a[3]);
    o.z = pack2(a[4], a[5]);
    o.w = pack2(a[6], a[7]);
    *(uint4*)(qout + (size_t)q * 256 + h * 32 + (dg << 3)) = o;
}

// ---------------------------------------------------------------------------
extern "C" void kernel_launch(void* const* d_in, const int* in_sizes, int n_in,
                              void* d_out, int out_size, void* d_ws, size_t ws_size,
                              hipStream_t stream)
{
    const float* query  = (const float*)d_in[0];
    const float* qpos   = (const float*)d_in[1];
    const float* fm     = (const float*)d_in[3];
    const int*   qlvl   = (const int*)d_in[5];
    const float* W_off  = (const float*)d_in[6];
    const float* b_off  = (const float*)d_in[7];
    const float* W_attn = (const float*)d_in[8];
    const float* b_attn = (const float*)d_in[9];
    const float* W_val  = (const float*)d_in[10];
    const float* b_val  = (const float*)d_in[11];
    const float* W_out  = (const float*)d_in[12];
    const float* b_out  = (const float*)d_in[13];
    float* out = (float*)d_out;

    char* ws = (char*)d_ws;
    unsigned short* WtAll   = (unsigned short*)ws;                     // 896*256 bf16
    unsigned short* values  = WtAll + (size_t)896 * 256;               // NQ*256 bf16
    unsigned short* qout    = values + (size_t)NQ * 256;               // NQ*256 bf16
    float*          offattn = (float*)(qout + (size_t)NQ * 256);       // NQ*384 f32

    dim3 blk(256);
    prepW_k<<<dim3(56), blk, 0, stream>>>(W_val, W_off, W_attn, W_out, WtAll);
    gemm_fused_k<<<dim3(170, 5), blk, 0, stream>>>(query, fm, nullptr, WtAll,
                                                   b_val, b_off, b_attn, b_out,
                                                   values, offattn, out, 0);
    sample_k<<<dim3(NQ / 8), blk, 0, stream>>>(offattn, values, qpos, qlvl, qout);
    gemm_fused_k<<<dim3(170, 2), blk, 0, stream>>>(query, fm, qout, WtAll,
                                                   b_val, b_off, b_attn, b_out,
                                                   values, offattn, out, 1);
}